// Round 11
// baseline (102.805 us; speedup 1.0000x reference)
//
#include <hip/hip_runtime.h>
#include <hip/hip_fp16.h>
#include <cstddef>

// ICTDIrrepsE3Conv — round 11.
//  - gates = f(edge_length) only -> 8192-entry lerp table
//  - atom-type factorization: rows[10][8], B[10][3][8][16] precomputed
//  - CSR gather, streaming M accumulation + per-atom B finish
//  - fp16-packed records split into pairs[E][8] u32 (32B) + asrc8[E] u8
//  - rank trick: no atomics in edge_kernel
//  - NEW: gather grid-strides node-groups (2048 blocks) -> s_B staging
//    amortized ~5x (was 150MB L2 traffic across 10K blocks)
//  - NEW: single-kernel scan (each block sums predecessor chunks inline),
//    6 -> 5 launches

#define TBL_N 8192
#define TBL_SCALE 1024.0f   // TBL_N / 8.0 range

__device__ __forceinline__ float silu(float x) {
    return x / (1.0f + __expf(-x));
}

__device__ __forceinline__ unsigned pack_half2(float lo, float hi) {
    unsigned a = __half_as_ushort(__float2half_rn(lo));
    unsigned b = __half_as_ushort(__float2half_rn(hi));
    return (b << 16) | a;
}

// ---- fused setup: blocks [0,zb) zero deg; [zb,zb+n_atom) rows+B;
//      [zb+n_atom, ...) table ----
__global__ __launch_bounds__(256) void setup_kernel(
    const float* __restrict__ emb_table,
    const float* __restrict__ w1, const float* __restrict__ b1,
    const float* __restrict__ w2, const float* __restrict__ b2,
    const float* __restrict__ tp_w,
    const float* __restrict__ fc_w1, const float* __restrict__ fc_b1,
    const float* __restrict__ fc_w2, const float* __restrict__ fc_b2,
    const float* __restrict__ fc_w3, const float* __restrict__ fc_b3,
    float* __restrict__ rows_g, float* __restrict__ B_g,
    float4* __restrict__ table,
    int4* __restrict__ deg4, int n4, int zb, int n_atom)
{
    int bid = blockIdx.x;
    int tid = threadIdx.x;

    if (bid < zb) {
        int i = bid * 256 + tid;
        if (i < n4) deg4[i] = make_int4(0, 0, 0, 0);
        return;
    }
    if (bid < zb + n_atom) {
        __shared__ float s_r[8];
        int a = bid - zb;
        if (tid < 8) {
            float e[16];
            #pragma unroll
            for (int i = 0; i < 16; i++) e[i] = emb_table[a * 16 + i];
            float acc_j = b2[tid];
            for (int k = 0; k < 64; k++) {
                float acc = b1[k];
                #pragma unroll
                for (int i = 0; i < 16; i++) acc = fmaf(e[i], w1[i * 64 + k], acc);
                acc_j = fmaf(silu(acc), w2[k * 8 + tid], acc_j);
            }
            s_r[tid] = acc_j;
            rows_g[a * 8 + tid] = acc_j;
        }
        __syncthreads();
        for (int t = tid; t < 384; t += 256) {
            int pp = t >> 7, ub = (t >> 4) & 7, wb = t & 15;
            int P = (pp == 0) ? 0 : (pp == 1) ? 3 : 9;
            float acc = 0.0f;
            #pragma unroll
            for (int v = 0; v < 8; v++)
                acc = fmaf(s_r[v], tp_w[P * 1024 + (ub * 8 + v) * 16 + wb], acc);
            B_g[a * 384 + t] = acc;
        }
        return;
    }

    // table: 4 samples per block, 1 wave per sample
    __shared__ float s_h1[4][64];
    int tb = bid - zb - n_atom;
    int s = tid >> 6;
    int k = tid & 63;
    int samp = tb * 4 + s;
    float len = (float)samp * (1.0f / TBL_SCALE);

    float emb[16];
    const float inv_step = 17.0f / 5.0f;
    #pragma unroll
    for (int b = 0; b < 16; b++) {
        float d = len * inv_step - (float)(b + 1);
        emb[b] = __expf(-d * d) * 3.5714285714285716f; // 4/1.12
    }

    float acc = fc_b1[k];
    #pragma unroll
    for (int b = 0; b < 16; b++) acc = fmaf(emb[b], fc_w1[b * 64 + k], acc);
    s_h1[s][k] = silu(acc);
    __syncthreads();

    float acc2 = fc_b2[k];
    #pragma unroll
    for (int j = 0; j < 64; j++)
        acc2 = fmaf(s_h1[s][j], fc_w2[j * 64 + k], acc2);
    float h2 = silu(acc2);

    float p0 = h2 * fc_w3[k * 15 + 0];
    float p3 = h2 * fc_w3[k * 15 + 3];
    float p9 = h2 * fc_w3[k * 15 + 9];
    #pragma unroll
    for (int off = 32; off > 0; off >>= 1) {
        p0 += __shfl_down(p0, off, 64);
        p3 += __shfl_down(p3, off, 64);
        p9 += __shfl_down(p9, off, 64);
    }
    if (k == 0) {
        table[samp] = make_float4((fc_b3[0] + p0) * 0.125f,
                                  (fc_b3[3] + p3) * 0.125f,
                                  (fc_b3[9] + p9) * 0.125f, 0.0f);
    }
}

// ---- degree histogram + per-edge rank within its dst bucket ----
__global__ __launch_bounds__(256) void deg_kernel(
    const int* __restrict__ edge_dst, int* __restrict__ deg,
    int* __restrict__ rank, int n_edges)
{
    int e = blockIdx.x * blockDim.x + threadIdx.x;
    if (e >= n_edges) return;
    rank[e] = atomicAdd(&deg[edge_dst[e]], 1);
}

// ---- single-pass scan: block b sums chunks [0,b) inline, scans its own ----
__global__ __launch_bounds__(1024) void scan_kernel(
    const int* __restrict__ deg, int* __restrict__ starts, int n)
{
    __shared__ int s[1024];
    __shared__ int red[1024];
    int tid = threadIdx.x;
    int b = blockIdx.x;

    // base = sum of all prior chunks
    int acc = 0;
    for (int c = 0; c < b; c++) {
        int idx = c * 1024 + tid;
        acc += (idx < n) ? deg[idx] : 0;
    }
    red[tid] = acc;
    __syncthreads();
    #pragma unroll
    for (int off = 512; off > 0; off >>= 1) {
        if (tid < off) red[tid] += red[tid + off];
        __syncthreads();
    }
    int base = red[0];

    // inclusive scan of own chunk
    int i = b * 1024 + tid;
    int v = (i < n) ? deg[i] : 0;
    s[tid] = v;
    __syncthreads();
    #pragma unroll
    for (int off = 1; off < 1024; off <<= 1) {
        int t1 = (tid >= off) ? s[tid - off] : 0;
        __syncthreads();
        s[tid] += t1;
        __syncthreads();
    }
    if (i < n) starts[i] = base + s[tid] - v;
}

// ---- per-edge: geometry + table-lerp gates + 32B pairs + 1B asrc ----
// pairs[slot][k] = half2(G_k, G8), k=0..7; asrc8[slot] = atom type of src
__global__ __launch_bounds__(256) void edge_kernel(
    const float* __restrict__ pos,
    const int* __restrict__ A,
    const int* __restrict__ batch,
    const int* __restrict__ edge_src,
    const int* __restrict__ edge_dst,
    const float* __restrict__ edge_shifts,
    const float* __restrict__ cell,
    const float4* __restrict__ table,
    const int* __restrict__ starts,
    const int* __restrict__ rank,
    unsigned* __restrict__ pairs,
    unsigned char* __restrict__ asrc8,
    int n_edges)
{
    int e = blockIdx.x * blockDim.x + threadIdx.x;
    if (e >= n_edges) return;

    int src = edge_src[e];
    int dst = edge_dst[e];

    float sh0 = edge_shifts[3 * (size_t)e + 0];
    float sh1 = edge_shifts[3 * (size_t)e + 1];
    float sh2 = edge_shifts[3 * (size_t)e + 2];
    int g = batch[src];
    const float* C = cell + (size_t)g * 9;
    float shx = sh0 * C[0] + sh1 * C[3] + sh2 * C[6];
    float shy = sh0 * C[1] + sh1 * C[4] + sh2 * C[7];
    float shz = sh0 * C[2] + sh1 * C[5] + sh2 * C[8];

    float vx = pos[3 * (size_t)dst + 0] - pos[3 * (size_t)src + 0] + shx;
    float vy = pos[3 * (size_t)dst + 1] - pos[3 * (size_t)src + 1] + shy;
    float vz = pos[3 * (size_t)dst + 2] - pos[3 * (size_t)src + 2] + shz;

    float len = sqrtf(vx * vx + vy * vy + vz * vz);
    float invl = 1.0f / fmaxf(len, 1e-8f);
    float nx = vx * invl, ny = vy * invl, nz = vz * invl;

    float t = fminf(len * TBL_SCALE, (float)(TBL_N - 1));
    int i0 = (int)t;
    i0 = min(i0, TBL_N - 2);
    float fr = t - (float)i0;
    float4 T0 = table[i0];
    float4 T1 = table[i0 + 1];
    float g0 = fmaf(fr, T1.x - T0.x, T0.x);
    float g1 = fmaf(fr, T1.y - T0.y, T0.y);
    float g2 = fmaf(fr, T1.z - T0.z, T0.z);

    const float s3  = 1.7320508075688772f;
    const float s15 = 3.872983346207417f;
    const float s5  = 2.23606797749979f;
    float G0 = g0;
    float G1 = g1 * s3 * ny, G2 = g1 * s3 * nz, G3 = g1 * s3 * nx;
    float G4 = g2 * s15 * nx * ny;
    float G5 = g2 * s15 * ny * nz;
    float G6 = g2 * 0.5f * s5 * (3.0f * nz * nz - 1.0f);
    float G7 = g2 * s15 * nx * nz;
    float G8 = g2 * 0.5f * s15 * (nx * nx - ny * ny);

    int asrc = A[src];
    int slot = starts[dst] + rank[e];

    unsigned u0 = pack_half2(G0, G8);
    unsigned u1 = pack_half2(G1, G8);
    unsigned u2 = pack_half2(G2, G8);
    unsigned u3 = pack_half2(G3, G8);
    unsigned u4 = pack_half2(G4, G8);
    unsigned u5 = pack_half2(G5, G8);
    unsigned u6 = pack_half2(G6, G8);
    unsigned u7 = pack_half2(G7, G8);

    uint4* pp = (uint4*)(pairs + (size_t)slot * 8);
    pp[0] = make_uint4(u0, u1, u2, u3);
    pp[1] = make_uint4(u4, u5, u6, u7);
    asrc8[slot] = (unsigned char)asrc;
}

// ---- gather: grid-stride node-groups; per-wave node; per-atom B finish ----
__global__ __launch_bounds__(256) void gather_kernel(
    const unsigned* __restrict__ pairs,
    const unsigned char* __restrict__ asrc8,
    const int* __restrict__ starts,
    const int* __restrict__ deg,
    const int* __restrict__ A,
    const float* __restrict__ rows_g,
    const float* __restrict__ B_g,
    float* __restrict__ out, int n_nodes, int n_atom, int n_groups)
{
    __shared__ float s_B[3840];      // [a][pp*128 + u*16 + w]
    __shared__ float s_rows[80];     // [a][u]
    __shared__ float s_M[4][80];     // per wave: [i'*8 + u], i' in 0..8

    int tid = threadIdx.x;
    {
        float4* dB = (float4*)s_B;
        const float4* sB = (const float4*)B_g;
        int nB4 = n_atom * 96;
        for (int t = tid; t < nB4; t += 256) dB[t] = sB[t];
        if (tid < n_atom * 8) s_rows[tid] = rows_g[tid];
    }
    __syncthreads();

    int wv = tid >> 6;
    int lane = tid & 63;
    int iq = lane >> 3, u = lane & 7;

    for (int grp = blockIdx.x; grp < n_groups; grp += gridDim.x) {
        int node = grp * 4 + wv;
        if (node >= n_nodes) continue;

        int start = starts[node];
        int d = deg[node];
        int anode = A[node];

        // phase 1: streaming M accumulation; 1 dword + 1 broadcast byte/edge
        float m = 0.0f, m8 = 0.0f;
        const unsigned* recs = pairs + (size_t)start * 8;
        const unsigned char* ap = asrc8 + start;
        int j = 0;
        for (; j + 4 <= d; j += 4) {
            unsigned q0 = recs[(size_t)(j + 0) * 8 + iq];
            unsigned q1 = recs[(size_t)(j + 1) * 8 + iq];
            unsigned q2 = recs[(size_t)(j + 2) * 8 + iq];
            unsigned q3 = recs[(size_t)(j + 3) * 8 + iq];
            int a0 = ap[j + 0], a1 = ap[j + 1], a2 = ap[j + 2], a3 = ap[j + 3];
            float2 p0 = __half22float2(*reinterpret_cast<const __half2*>(&q0));
            float2 p1 = __half22float2(*reinterpret_cast<const __half2*>(&q1));
            float2 p2 = __half22float2(*reinterpret_cast<const __half2*>(&q2));
            float2 p3 = __half22float2(*reinterpret_cast<const __half2*>(&q3));
            float c0 = s_rows[a0 * 8 + u];
            float c1 = s_rows[a1 * 8 + u];
            float c2 = s_rows[a2 * 8 + u];
            float c3 = s_rows[a3 * 8 + u];
            m  = fmaf(p0.x, c0, m);  m8 = fmaf(p0.y, c0, m8);
            m  = fmaf(p1.x, c1, m);  m8 = fmaf(p1.y, c1, m8);
            m  = fmaf(p2.x, c2, m);  m8 = fmaf(p2.y, c2, m8);
            m  = fmaf(p3.x, c3, m);  m8 = fmaf(p3.y, c3, m8);
        }
        for (; j < d; j++) {
            unsigned q0 = recs[(size_t)j * 8 + iq];
            int a0 = ap[j];
            float2 p0 = __half22float2(*reinterpret_cast<const __half2*>(&q0));
            float c0 = s_rows[a0 * 8 + u];
            m  = fmaf(p0.x, c0, m);
            m8 = fmaf(p0.y, c0, m8);
        }
        s_M[wv][iq * 8 + u] = m;
        if (lane < 8) s_M[wv][64 + u] = m8;

        // phase 2: 144 contractions of length 8 against per-atom B
        const float* Bn = s_B + anode * 384;
        float invd = 1.0f / fmaxf((float)d, 1.0f);
        float* row = out + (size_t)node * 144;
        {
            int c = lane;
            int pp, w, ip;
            if (c < 16) { pp = 0; w = c; ip = 0; }
            else { int t = c - 16; pp = 1; w = t / 3; ip = 1 + (t - 3 * (t / 3)); }
            float acc = 0.0f;
            #pragma unroll
            for (int uu = 0; uu < 8; uu++)
                acc = fmaf(Bn[pp * 128 + uu * 16 + w], s_M[wv][ip * 8 + uu], acc);
            row[c] = acc * invd;
        }
        {
            int t = lane;                      // c = 64 + lane
            int w = t / 5; int i = t - 5 * w;
            float acc = 0.0f;
            #pragma unroll
            for (int uu = 0; uu < 8; uu++)
                acc = fmaf(Bn[256 + uu * 16 + w], s_M[wv][(4 + i) * 8 + uu], acc);
            row[64 + lane] = acc * invd;
        }
        if (lane < 16) {
            int t = 64 + lane;                 // c = 128 + lane
            int w = t / 5; int i = t - 5 * w;
            float acc = 0.0f;
            #pragma unroll
            for (int uu = 0; uu < 8; uu++)
                acc = fmaf(Bn[256 + uu * 16 + w], s_M[wv][(4 + i) * 8 + uu], acc);
            row[128 + lane] = acc * invd;
        }
    }
}

extern "C" void kernel_launch(void* const* d_in, const int* in_sizes, int n_in,
                              void* d_out, int out_size, void* d_ws, size_t ws_size,
                              hipStream_t stream)
{
    const float* pos         = (const float*)d_in[0];
    const int*   A           = (const int*)d_in[1];
    const int*   batch       = (const int*)d_in[2];
    const int*   edge_src    = (const int*)d_in[3];
    const int*   edge_dst    = (const int*)d_in[4];
    const float* edge_shifts = (const float*)d_in[5];
    const float* cell        = (const float*)d_in[6];
    const float* emb_table   = (const float*)d_in[7];
    const float* mlp_w1      = (const float*)d_in[8];
    const float* mlp_b1      = (const float*)d_in[9];
    const float* mlp_w2      = (const float*)d_in[10];
    const float* mlp_b2      = (const float*)d_in[11];
    const float* fc_w1       = (const float*)d_in[12];
    const float* fc_b1       = (const float*)d_in[13];
    const float* fc_w2       = (const float*)d_in[14];
    const float* fc_b2       = (const float*)d_in[15];
    const float* fc_w3       = (const float*)d_in[16];
    const float* fc_b3       = (const float*)d_in[17];
    const float* tp_w        = (const float*)d_in[18];

    int n_nodes = in_sizes[1];
    int n_edges = in_sizes[3];
    int n_atom  = in_sizes[7] / 16;
    int nb      = (n_nodes + 1023) / 1024;

    // ws layout
    float*         table   = (float*)d_ws;                     // TBL_N*4 floats
    float*         rows_g  = table + (size_t)TBL_N * 4;        // 128 (80 used)
    float*         B_g     = rows_g + 128;                     // 3840
    int*           deg     = (int*)(B_g + 3840);               // n_nodes
    int*           starts  = deg + n_nodes;                    // n_nodes
    int*           rank    = starts + n_nodes;                 // n_edges
    unsigned*      pairs   = (unsigned*)(rank + n_edges);      // n_edges*8 u32
    unsigned char* asrc8   = (unsigned char*)(pairs + (size_t)n_edges * 8);

    int n4 = (n_nodes + 3) / 4;
    int zb = (n4 + 255) / 256;

    setup_kernel<<<zb + n_atom + TBL_N / 4, 256, 0, stream>>>(
        emb_table, mlp_w1, mlp_b1, mlp_w2, mlp_b2, tp_w,
        fc_w1, fc_b1, fc_w2, fc_b2, fc_w3, fc_b3,
        rows_g, B_g, (float4*)table, (int4*)deg, n4, zb, n_atom);

    deg_kernel<<<(n_edges + 255) / 256, 256, 0, stream>>>(
        edge_dst, deg, rank, n_edges);

    scan_kernel<<<nb, 1024, 0, stream>>>(deg, starts, n_nodes);

    edge_kernel<<<(n_edges + 255) / 256, 256, 0, stream>>>(
        pos, A, batch, edge_src, edge_dst, edge_shifts, cell,
        (const float4*)table, starts, rank, pairs, asrc8, n_edges);

    int n_groups = (n_nodes + 3) / 4;
    int ggrid = n_groups < 2048 ? n_groups : 2048;
    gather_kernel<<<ggrid, 256, 0, stream>>>(
        pairs, asrc8, starts, deg, A, rows_g, B_g,
        (float*)d_out, n_nodes, n_atom, n_groups);
}

// Round 12
// 89.288 us; speedup vs baseline: 1.1514x; 1.1514x over previous
//
#include <hip/hip_runtime.h>
#include <hip/hip_fp16.h>
#include <cstddef>

// ICTDIrrepsE3Conv — round 12.
//  = round 10 kernel set (96.7us measured) + grid-stride gather ONLY.
//  Round 11 post-mortem: bundling {record split w/ byte sidecar, merged
//  O(b) scan, grid-stride} regressed to 102.8. Reverting the first two,
//  keeping grid-stride as the single A/B variable.
//  - gates = f(edge_length) only -> 8192-entry lerp table
//  - atom-type factorization: rows[10][8], B[10][3][8][16] precomputed
//  - fp16-packed 40B records: 8 x half2(G_k, G8) + asrc word
//  - rank trick: no atomics in edge_kernel
//  - two-kernel parallel scan (partial + scan_write)
//  - gather grid-strides node-groups at 2048 blocks (s_B staging amortized)

#define TBL_N 8192
#define TBL_SCALE 1024.0f   // TBL_N / 8.0 range

__device__ __forceinline__ float silu(float x) {
    return x / (1.0f + __expf(-x));
}

__device__ __forceinline__ unsigned pack_half2(float lo, float hi) {
    unsigned a = __half_as_ushort(__float2half_rn(lo));
    unsigned b = __half_as_ushort(__float2half_rn(hi));
    return (b << 16) | a;
}

// ---- fused setup: blocks [0,zb) zero deg; [zb,zb+n_atom) rows+B;
//      [zb+n_atom, ...) table ----
__global__ __launch_bounds__(256) void setup_kernel(
    const float* __restrict__ emb_table,
    const float* __restrict__ w1, const float* __restrict__ b1,
    const float* __restrict__ w2, const float* __restrict__ b2,
    const float* __restrict__ tp_w,
    const float* __restrict__ fc_w1, const float* __restrict__ fc_b1,
    const float* __restrict__ fc_w2, const float* __restrict__ fc_b2,
    const float* __restrict__ fc_w3, const float* __restrict__ fc_b3,
    float* __restrict__ rows_g, float* __restrict__ B_g,
    float4* __restrict__ table,
    int4* __restrict__ deg4, int n4, int zb, int n_atom)
{
    int bid = blockIdx.x;
    int tid = threadIdx.x;

    if (bid < zb) {
        int i = bid * 256 + tid;
        if (i < n4) deg4[i] = make_int4(0, 0, 0, 0);
        return;
    }
    if (bid < zb + n_atom) {
        __shared__ float s_r[8];
        int a = bid - zb;
        if (tid < 8) {
            float e[16];
            #pragma unroll
            for (int i = 0; i < 16; i++) e[i] = emb_table[a * 16 + i];
            float acc_j = b2[tid];
            for (int k = 0; k < 64; k++) {
                float acc = b1[k];
                #pragma unroll
                for (int i = 0; i < 16; i++) acc = fmaf(e[i], w1[i * 64 + k], acc);
                acc_j = fmaf(silu(acc), w2[k * 8 + tid], acc_j);
            }
            s_r[tid] = acc_j;
            rows_g[a * 8 + tid] = acc_j;
        }
        __syncthreads();
        for (int t = tid; t < 384; t += 256) {
            int pp = t >> 7, ub = (t >> 4) & 7, wb = t & 15;
            int P = (pp == 0) ? 0 : (pp == 1) ? 3 : 9;
            float acc = 0.0f;
            #pragma unroll
            for (int v = 0; v < 8; v++)
                acc = fmaf(s_r[v], tp_w[P * 1024 + (ub * 8 + v) * 16 + wb], acc);
            B_g[a * 384 + t] = acc;
        }
        return;
    }

    // table: 4 samples per block, 1 wave per sample
    __shared__ float s_h1[4][64];
    int tb = bid - zb - n_atom;
    int s = tid >> 6;
    int k = tid & 63;
    int samp = tb * 4 + s;
    float len = (float)samp * (1.0f / TBL_SCALE);

    float emb[16];
    const float inv_step = 17.0f / 5.0f;
    #pragma unroll
    for (int b = 0; b < 16; b++) {
        float d = len * inv_step - (float)(b + 1);
        emb[b] = __expf(-d * d) * 3.5714285714285716f; // 4/1.12
    }

    float acc = fc_b1[k];
    #pragma unroll
    for (int b = 0; b < 16; b++) acc = fmaf(emb[b], fc_w1[b * 64 + k], acc);
    s_h1[s][k] = silu(acc);
    __syncthreads();

    float acc2 = fc_b2[k];
    #pragma unroll
    for (int j = 0; j < 64; j++)
        acc2 = fmaf(s_h1[s][j], fc_w2[j * 64 + k], acc2);
    float h2 = silu(acc2);

    float p0 = h2 * fc_w3[k * 15 + 0];
    float p3 = h2 * fc_w3[k * 15 + 3];
    float p9 = h2 * fc_w3[k * 15 + 9];
    #pragma unroll
    for (int off = 32; off > 0; off >>= 1) {
        p0 += __shfl_down(p0, off, 64);
        p3 += __shfl_down(p3, off, 64);
        p9 += __shfl_down(p9, off, 64);
    }
    if (k == 0) {
        table[samp] = make_float4((fc_b3[0] + p0) * 0.125f,
                                  (fc_b3[3] + p3) * 0.125f,
                                  (fc_b3[9] + p9) * 0.125f, 0.0f);
    }
}

// ---- degree histogram + per-edge rank within its dst bucket ----
__global__ __launch_bounds__(256) void deg_kernel(
    const int* __restrict__ edge_dst, int* __restrict__ deg,
    int* __restrict__ rank, int n_edges)
{
    int e = blockIdx.x * blockDim.x + threadIdx.x;
    if (e >= n_edges) return;
    rank[e] = atomicAdd(&deg[edge_dst[e]], 1);
}

__global__ __launch_bounds__(1024) void partial_kernel(
    const int* __restrict__ deg, int* __restrict__ bsum, int n)
{
    __shared__ int red[1024];
    int tid = threadIdx.x;
    int i = blockIdx.x * 1024 + tid;
    red[tid] = (i < n) ? deg[i] : 0;
    __syncthreads();
    #pragma unroll
    for (int off = 512; off > 0; off >>= 1) {
        if (tid < off) red[tid] += red[tid + off];
        __syncthreads();
    }
    if (tid == 0) bsum[blockIdx.x] = red[0];
}

__global__ __launch_bounds__(1024) void scan_write_kernel(
    const int* __restrict__ deg, const int* __restrict__ bsum,
    int* __restrict__ starts, int n, int nb)
{
    __shared__ int s[1024];
    __shared__ int sb[1024];
    int tid = threadIdx.x;

    sb[tid] = (tid < nb) ? bsum[tid] : 0;
    int i = blockIdx.x * 1024 + tid;
    int v = (i < n) ? deg[i] : 0;
    s[tid] = v;
    __syncthreads();
    #pragma unroll
    for (int off = 1; off < 1024; off <<= 1) {
        int t1 = (tid >= off) ? s[tid - off] : 0;
        int t2 = (tid >= off) ? sb[tid - off] : 0;
        __syncthreads();
        s[tid] += t1;
        sb[tid] += t2;
        __syncthreads();
    }
    int base = (blockIdx.x == 0) ? 0 : sb[blockIdx.x - 1];
    if (i < n) starts[i] = base + s[tid] - v;
}

// ---- per-edge: geometry + table-lerp gates + 40B fp16 record ----
// record (10 floats): words 0..7 = half2(G_k, G8), word 8 = asrc, word 9 pad
__global__ __launch_bounds__(256) void edge_kernel(
    const float* __restrict__ pos,
    const int* __restrict__ A,
    const int* __restrict__ batch,
    const int* __restrict__ edge_src,
    const int* __restrict__ edge_dst,
    const float* __restrict__ edge_shifts,
    const float* __restrict__ cell,
    const float4* __restrict__ table,
    const int* __restrict__ starts,
    const int* __restrict__ rank,
    float* __restrict__ records,
    int n_edges)
{
    int e = blockIdx.x * blockDim.x + threadIdx.x;
    if (e >= n_edges) return;

    int src = edge_src[e];
    int dst = edge_dst[e];

    float sh0 = edge_shifts[3 * (size_t)e + 0];
    float sh1 = edge_shifts[3 * (size_t)e + 1];
    float sh2 = edge_shifts[3 * (size_t)e + 2];
    int g = batch[src];
    const float* C = cell + (size_t)g * 9;
    float shx = sh0 * C[0] + sh1 * C[3] + sh2 * C[6];
    float shy = sh0 * C[1] + sh1 * C[4] + sh2 * C[7];
    float shz = sh0 * C[2] + sh1 * C[5] + sh2 * C[8];

    float vx = pos[3 * (size_t)dst + 0] - pos[3 * (size_t)src + 0] + shx;
    float vy = pos[3 * (size_t)dst + 1] - pos[3 * (size_t)src + 1] + shy;
    float vz = pos[3 * (size_t)dst + 2] - pos[3 * (size_t)src + 2] + shz;

    float len = sqrtf(vx * vx + vy * vy + vz * vz);
    float invl = 1.0f / fmaxf(len, 1e-8f);
    float nx = vx * invl, ny = vy * invl, nz = vz * invl;

    float t = fminf(len * TBL_SCALE, (float)(TBL_N - 1));
    int i0 = (int)t;
    i0 = min(i0, TBL_N - 2);
    float fr = t - (float)i0;
    float4 T0 = table[i0];
    float4 T1 = table[i0 + 1];
    float g0 = fmaf(fr, T1.x - T0.x, T0.x);
    float g1 = fmaf(fr, T1.y - T0.y, T0.y);
    float g2 = fmaf(fr, T1.z - T0.z, T0.z);

    const float s3  = 1.7320508075688772f;
    const float s15 = 3.872983346207417f;
    const float s5  = 2.23606797749979f;
    float G0 = g0;
    float G1 = g1 * s3 * ny, G2 = g1 * s3 * nz, G3 = g1 * s3 * nx;
    float G4 = g2 * s15 * nx * ny;
    float G5 = g2 * s15 * ny * nz;
    float G6 = g2 * 0.5f * s5 * (3.0f * nz * nz - 1.0f);
    float G7 = g2 * s15 * nx * nz;
    float G8 = g2 * 0.5f * s15 * (nx * nx - ny * ny);

    int asrc = A[src];
    int slot = starts[dst] + rank[e];

    unsigned u0 = pack_half2(G0, G8);
    unsigned u1 = pack_half2(G1, G8);
    unsigned u2 = pack_half2(G2, G8);
    unsigned u3 = pack_half2(G3, G8);
    unsigned u4 = pack_half2(G4, G8);
    unsigned u5 = pack_half2(G5, G8);
    unsigned u6 = pack_half2(G6, G8);
    unsigned u7 = pack_half2(G7, G8);

    float2* r2 = (float2*)(records + (size_t)slot * 10);
    r2[0] = make_float2(__uint_as_float(u0), __uint_as_float(u1));
    r2[1] = make_float2(__uint_as_float(u2), __uint_as_float(u3));
    r2[2] = make_float2(__uint_as_float(u4), __uint_as_float(u5));
    r2[3] = make_float2(__uint_as_float(u6), __uint_as_float(u7));
    r2[4] = make_float2(__int_as_float(asrc), 0.0f);
}

// ---- gather: grid-stride node-groups; wave per node; per-atom B finish ----
__global__ __launch_bounds__(256) void gather_kernel(
    const float* __restrict__ records,
    const int* __restrict__ starts,
    const int* __restrict__ deg,
    const int* __restrict__ A,
    const float* __restrict__ rows_g,
    const float* __restrict__ B_g,
    float* __restrict__ out, int n_nodes, int n_atom, int n_groups)
{
    __shared__ float s_B[3840];      // [a][pp*128 + u*16 + w]
    __shared__ float s_rows[80];     // [a][u]
    __shared__ float s_M[4][80];     // per wave: [i'*8 + u], i' in 0..8

    int tid = threadIdx.x;
    {
        float4* dB = (float4*)s_B;
        const float4* sB = (const float4*)B_g;
        int nB4 = n_atom * 96;
        for (int t = tid; t < nB4; t += 256) dB[t] = sB[t];
        if (tid < n_atom * 8) s_rows[tid] = rows_g[tid];
    }
    __syncthreads();

    int wv = tid >> 6;
    int lane = tid & 63;
    int iq = lane >> 3, u = lane & 7;

    for (int grp = blockIdx.x; grp < n_groups; grp += gridDim.x) {
        int node = grp * 4 + wv;
        if (node >= n_nodes) continue;

        int start = starts[node];
        int d = deg[node];
        int anode = A[node];

        // phase 1: streaming M accumulation; 2 dword loads per edge
        float m = 0.0f, m8 = 0.0f;
        const float* recs = records + (size_t)start * 10;
        int j = 0;
        for (; j + 4 <= d; j += 4) {
            const unsigned* r0 = (const unsigned*)(recs + (size_t)(j + 0) * 10);
            const unsigned* r1 = (const unsigned*)(recs + (size_t)(j + 1) * 10);
            const unsigned* r2 = (const unsigned*)(recs + (size_t)(j + 2) * 10);
            const unsigned* r3 = (const unsigned*)(recs + (size_t)(j + 3) * 10);
            unsigned q0 = r0[iq], q1 = r1[iq], q2 = r2[iq], q3 = r3[iq];
            int a0 = (int)r0[8], a1 = (int)r1[8], a2 = (int)r2[8], a3 = (int)r3[8];
            float2 p0 = __half22float2(*reinterpret_cast<const __half2*>(&q0));
            float2 p1 = __half22float2(*reinterpret_cast<const __half2*>(&q1));
            float2 p2 = __half22float2(*reinterpret_cast<const __half2*>(&q2));
            float2 p3 = __half22float2(*reinterpret_cast<const __half2*>(&q3));
            float c0 = s_rows[a0 * 8 + u];
            float c1 = s_rows[a1 * 8 + u];
            float c2 = s_rows[a2 * 8 + u];
            float c3 = s_rows[a3 * 8 + u];
            m  = fmaf(p0.x, c0, m);  m8 = fmaf(p0.y, c0, m8);
            m  = fmaf(p1.x, c1, m);  m8 = fmaf(p1.y, c1, m8);
            m  = fmaf(p2.x, c2, m);  m8 = fmaf(p2.y, c2, m8);
            m  = fmaf(p3.x, c3, m);  m8 = fmaf(p3.y, c3, m8);
        }
        for (; j < d; j++) {
            const unsigned* r0 = (const unsigned*)(recs + (size_t)j * 10);
            unsigned q0 = r0[iq];
            int a0 = (int)r0[8];
            float2 p0 = __half22float2(*reinterpret_cast<const __half2*>(&q0));
            float c0 = s_rows[a0 * 8 + u];
            m  = fmaf(p0.x, c0, m);
            m8 = fmaf(p0.y, c0, m8);
        }
        s_M[wv][iq * 8 + u] = m;
        if (lane < 8) s_M[wv][64 + u] = m8;   // only iq==0 lanes' m8 consumed

        // phase 2: 144 contractions of length 8 against per-atom B
        const float* Bn = s_B + anode * 384;
        float invd = 1.0f / fmaxf((float)d, 1.0f);
        float* row = out + (size_t)node * 144;
        {
            int c = lane;
            int pp, w, ip;
            if (c < 16) { pp = 0; w = c; ip = 0; }
            else { int t = c - 16; pp = 1; w = t / 3; ip = 1 + (t - 3 * (t / 3)); }
            float acc = 0.0f;
            #pragma unroll
            for (int uu = 0; uu < 8; uu++)
                acc = fmaf(Bn[pp * 128 + uu * 16 + w], s_M[wv][ip * 8 + uu], acc);
            row[c] = acc * invd;
        }
        {
            int t = lane;                      // c = 64 + lane
            int w = t / 5; int i = t - 5 * w;
            float acc = 0.0f;
            #pragma unroll
            for (int uu = 0; uu < 8; uu++)
                acc = fmaf(Bn[256 + uu * 16 + w], s_M[wv][(4 + i) * 8 + uu], acc);
            row[64 + lane] = acc * invd;
        }
        if (lane < 16) {
            int t = 64 + lane;                 // c = 128 + lane
            int w = t / 5; int i = t - 5 * w;
            float acc = 0.0f;
            #pragma unroll
            for (int uu = 0; uu < 8; uu++)
                acc = fmaf(Bn[256 + uu * 16 + w], s_M[wv][(4 + i) * 8 + uu], acc);
            row[128 + lane] = acc * invd;
        }
    }
}

extern "C" void kernel_launch(void* const* d_in, const int* in_sizes, int n_in,
                              void* d_out, int out_size, void* d_ws, size_t ws_size,
                              hipStream_t stream)
{
    const float* pos         = (const float*)d_in[0];
    const int*   A           = (const int*)d_in[1];
    const int*   batch       = (const int*)d_in[2];
    const int*   edge_src    = (const int*)d_in[3];
    const int*   edge_dst    = (const int*)d_in[4];
    const float* edge_shifts = (const float*)d_in[5];
    const float* cell        = (const float*)d_in[6];
    const float* emb_table   = (const float*)d_in[7];
    const float* mlp_w1      = (const float*)d_in[8];
    const float* mlp_b1      = (const float*)d_in[9];
    const float* mlp_w2      = (const float*)d_in[10];
    const float* mlp_b2      = (const float*)d_in[11];
    const float* fc_w1       = (const float*)d_in[12];
    const float* fc_b1       = (const float*)d_in[13];
    const float* fc_w2       = (const float*)d_in[14];
    const float* fc_b2       = (const float*)d_in[15];
    const float* fc_w3       = (const float*)d_in[16];
    const float* fc_b3       = (const float*)d_in[17];
    const float* tp_w        = (const float*)d_in[18];

    int n_nodes = in_sizes[1];
    int n_edges = in_sizes[3];
    int n_atom  = in_sizes[7] / 16;
    int nb      = (n_nodes + 1023) / 1024;

    // ws layout
    float* table   = (float*)d_ws;                        // TBL_N*4 floats
    float* rows_g  = table + (size_t)TBL_N * 4;           // 128 (80 used)
    float* B_g     = rows_g + 128;                        // 3840
    int*   deg     = (int*)(B_g + 3840);                  // n_nodes
    int*   starts  = deg + n_nodes;                       // n_nodes
    int*   bsum    = starts + n_nodes;                    // 1024
    int*   rank    = bsum + 1024;                         // n_edges
    float* records = (float*)(rank + n_edges);            // n_edges*10

    int n4 = (n_nodes + 3) / 4;
    int zb = (n4 + 255) / 256;

    setup_kernel<<<zb + n_atom + TBL_N / 4, 256, 0, stream>>>(
        emb_table, mlp_w1, mlp_b1, mlp_w2, mlp_b2, tp_w,
        fc_w1, fc_b1, fc_w2, fc_b2, fc_w3, fc_b3,
        rows_g, B_g, (float4*)table, (int4*)deg, n4, zb, n_atom);

    deg_kernel<<<(n_edges + 255) / 256, 256, 0, stream>>>(
        edge_dst, deg, rank, n_edges);

    partial_kernel<<<nb, 1024, 0, stream>>>(deg, bsum, n_nodes);

    scan_write_kernel<<<nb, 1024, 0, stream>>>(deg, bsum, starts, n_nodes, nb);

    edge_kernel<<<(n_edges + 255) / 256, 256, 0, stream>>>(
        pos, A, batch, edge_src, edge_dst, edge_shifts, cell,
        (const float4*)table, starts, rank, records, n_edges);

    int n_groups = (n_nodes + 3) / 4;
    int ggrid = n_groups < 2048 ? n_groups : 2048;
    gather_kernel<<<ggrid, 256, 0, stream>>>(
        records, starts, deg, A, rows_g, B_g,
        (float*)d_out, n_nodes, n_atom, n_groups);
}